// Round 1
// baseline (126.084 us; speedup 1.0000x reference)
//
#include <hip/hip_runtime.h>

#define Bc 2
#define Gc 8
#define Dc 32
#define Hc 128
#define Wc 160
#define DHW (Dc * Hc * Wc)   // 655360
#define HW (Hc * Wc)         // 20480

// ---------------------------------------------------------------------------
// Kernel 1: per-point MLP 8 -> 16 -> 8 -> 1 (BN folded into weights in LDS).
// One thread handles 4 consecutive w-points via float4 (W=160 divisible by 4,
// g-plane stride DHW divisible by 4 -> all float4 loads 16B aligned).
// ---------------------------------------------------------------------------
__global__ __launch_bounds__(256) void mlp_kernel(
    const float* __restrict__ x1,
    const float* __restrict__ w0, const float* __restrict__ s0, const float* __restrict__ b0,
    const float* __restrict__ w1, const float* __restrict__ s1, const float* __restrict__ b1,
    const float* __restrict__ wsim, const float* __restrict__ bsim,
    float* __restrict__ sim)
{
    __shared__ float sm[289];
    const int tid = threadIdx.x;
    for (int i = tid; i < 289; i += 256) {
        float v;
        if (i < 128)      v = w0[i] * s0[i >> 3];                    // w0f[o][g] = w0*scale0[o]
        else if (i < 144) v = b0[i - 128];                           // bias0[o]
        else if (i < 272) v = w1[i - 144] * s1[(i - 144) >> 4];      // w1f[c][o] = w1*scale1[c]
        else if (i < 280) v = b1[i - 272];                           // bias1[c]
        else if (i < 288) v = wsim[i - 280];                         // w_sim[c]
        else              v = bsim[0];                               // b_sim
        sm[i] = v;
    }
    __syncthreads();
    const float* sw0 = sm;
    const float* sb0 = sm + 128;
    const float* sw1 = sm + 144;
    const float* sb1 = sm + 272;
    const float* sws = sm + 280;
    const float  sbs = sm[288];

    const int t   = blockIdx.x * 256 + tid;   // 0 .. 327679 (exact grid)
    const int p   = t << 2;                   // base point index over (b,d,h,w)
    const int b   = p / DHW;
    const int dhw = p - b * DHW;
    const float* xb = x1 + (size_t)b * (Gc * DHW) + dhw;

    float4 xv[Gc];
#pragma unroll
    for (int g = 0; g < Gc; ++g)
        xv[g] = *reinterpret_cast<const float4*>(xb + g * DHW);

    // layer 0: 8 -> 16, relu
    float4 h0[16];
#pragma unroll
    for (int o = 0; o < 16; ++o) {
        float ax = sb0[o], ay = ax, az = ax, aw = ax;
#pragma unroll
        for (int g = 0; g < Gc; ++g) {
            const float wv = sw0[o * Gc + g];
            ax = fmaf(wv, xv[g].x, ax);
            ay = fmaf(wv, xv[g].y, ay);
            az = fmaf(wv, xv[g].z, az);
            aw = fmaf(wv, xv[g].w, aw);
        }
        h0[o].x = fmaxf(ax, 0.f);
        h0[o].y = fmaxf(ay, 0.f);
        h0[o].z = fmaxf(az, 0.f);
        h0[o].w = fmaxf(aw, 0.f);
    }

    // layer 1: 16 -> 8, relu; fused with sim projection 8 -> 1
    float sx = sbs, sy = sbs, sz = sbs, sw = sbs;
#pragma unroll
    for (int c = 0; c < 8; ++c) {
        float ax = sb1[c], ay = ax, az = ax, aw = ax;
#pragma unroll
        for (int o = 0; o < 16; ++o) {
            const float wv = sw1[c * 16 + o];
            ax = fmaf(wv, h0[o].x, ax);
            ay = fmaf(wv, h0[o].y, ay);
            az = fmaf(wv, h0[o].z, az);
            aw = fmaf(wv, h0[o].w, aw);
        }
        const float ws = sws[c];
        sx = fmaf(ws, fmaxf(ax, 0.f), sx);
        sy = fmaf(ws, fmaxf(ay, 0.f), sy);
        sz = fmaf(ws, fmaxf(az, 0.f), sz);
        sw = fmaf(ws, fmaxf(aw, 0.f), sw);
    }

    float4 r; r.x = sx; r.y = sy; r.z = sz; r.w = sw;
    *reinterpret_cast<float4*>(sim + p) = r;
}

// ---------------------------------------------------------------------------
// Kernel 2: 9-neighbor aggregation, dilations 2 (narrow, offset[s+9]) and
// 4 (wide, offset[s]), reflect padding, * 0.5 * weight.
// Thread = (b, d-group of 8, h, w); offsets + reflect indices hoisted out of
// the 8-deep d loop (offset/weight independent of d).
// ---------------------------------------------------------------------------
__global__ __launch_bounds__(256) void agg_kernel(
    const float* __restrict__ sim, const float* __restrict__ offset,
    const float* __restrict__ weight, float* __restrict__ out)
{
    const int l = blockIdx.x * 256 + threadIdx.x;  // 0 .. 163839 (exact grid)
    const int w = l % Wc;
    int r = l / Wc;
    const int h = r % Hc;
    r /= Hc;
    const int dg = r & 3;
    const int b  = r >> 2;

    float off[18];
#pragma unroll
    for (int s = 0; s < 18; ++s)
        off[s] = offset[((b * 18 + s) * Hc + h) * Wc + w];
    const float wt = weight[b * HW + h * Wc + w];

    int idx1[9], idx2[9];
#pragma unroll
    for (int iy = 0; iy < 3; ++iy) {
        int y1 = h + (iy - 1) * 2; y1 = y1 < 0 ? -y1 : (y1 >= Hc ? 2 * Hc - 2 - y1 : y1);
        int y2 = h + (iy - 1) * 4; y2 = y2 < 0 ? -y2 : (y2 >= Hc ? 2 * Hc - 2 - y2 : y2);
#pragma unroll
        for (int ix = 0; ix < 3; ++ix) {
            int x1c = w + (ix - 1) * 2; x1c = x1c < 0 ? -x1c : (x1c >= Wc ? 2 * Wc - 2 - x1c : x1c);
            int x2c = w + (ix - 1) * 4; x2c = x2c < 0 ? -x2c : (x2c >= Wc ? 2 * Wc - 2 - x2c : x2c);
            idx1[iy * 3 + ix] = y1 * Wc + x1c;
            idx2[iy * 3 + ix] = y2 * Wc + x2c;
        }
    }

    const size_t base = (size_t)(b * Dc + dg * 8) * HW;
    const float* sp0 = sim + base;
    float* op0 = out + base + h * Wc + w;
#pragma unroll
    for (int d = 0; d < 8; ++d) {
        const float* sp = sp0 + d * HW;
        float a = 0.f;
#pragma unroll
        for (int s = 0; s < 9; ++s)
            a = fmaf(off[s + 9], sp[idx1[s]], fmaf(off[s], sp[idx2[s]], a));
        op0[d * HW] = a * 0.5f * wt;
    }
}

extern "C" void kernel_launch(void* const* d_in, const int* in_sizes, int n_in,
                              void* d_out, int out_size, void* d_ws, size_t ws_size,
                              hipStream_t stream)
{
    const float* x1     = (const float*)d_in[0];
    const float* offset = (const float*)d_in[1];
    const float* weight = (const float*)d_in[2];
    const float* w0     = (const float*)d_in[3];
    const float* s0     = (const float*)d_in[4];
    const float* b0     = (const float*)d_in[5];
    const float* w1     = (const float*)d_in[6];
    const float* s1     = (const float*)d_in[7];
    const float* b1     = (const float*)d_in[8];
    const float* wsim   = (const float*)d_in[9];
    const float* bsim   = (const float*)d_in[10];
    float* out = (float*)d_out;
    float* sim = (float*)d_ws;   // B*D*H*W floats = 5.25 MB scratch

    // 327680 point-quads / 256 threads = 1280 blocks (exact)
    mlp_kernel<<<1280, 256, 0, stream>>>(x1, w0, s0, b0, w1, s1, b1, wsim, bsim, sim);
    // 163840 (b,dg,h,w) threads / 256 = 640 blocks (exact)
    agg_kernel<<<640, 256, 0, stream>>>(sim, offset, weight, out);
}